// Round 10
// baseline (295.427 us; speedup 1.0000x reference)
//
#include <hip/hip_runtime.h>
#include <hip/hip_bf16.h>

typedef _Float16 half8v __attribute__((ext_vector_type(8)));
typedef __fp16  fp16x2 __attribute__((ext_vector_type(2)));   // cvt_pkrtz return type
typedef float floatx4 __attribute__((ext_vector_type(4)));

#define NB 32
#define NT 2048
#define ND 1024
#define NM (NB * NT)

// global->LDS direct DMA, 16B per lane. Linear LDS dest; swizzle on the
// GLOBAL source address (rule #21).
#define GL16(g, l)                                                             \
    __builtin_amdgcn_global_load_lds(                                          \
        (const __attribute__((address_space(1))) void*)(g),                    \
        (__attribute__((address_space(3))) void*)(l), 16, 0, 0)

__device__ __forceinline__ float fast_tanh(float x) {
    x = fminf(9.0f, fmaxf(-9.0f, x));
    float e = __builtin_amdgcn_exp2f(x * 2.8853900817779268f); // e^(2x)
    return (e - 1.0f) * __builtin_amdgcn_rcpf(e + 1.0f);
}

// ---------------- zero out + logits (replaces slow fillBuffer) ----------------
__global__ __launch_bounds__(256)
void zero_kernel(float* __restrict__ out, float* __restrict__ logits) {
    int i = blockIdx.x * 256 + threadIdx.x;      // grid 256 -> 65536 threads
    logits[i] = 0.f;
    if (i < NB * ND) out[i] = 0.f;
}

// ---------------- W [K][N] f32  ->  Wt [N][K] fp16 ----------------
__global__ __launch_bounds__(256)
void wt_kernel(const float* __restrict__ W, _Float16* __restrict__ Wt) {
    __shared__ float tile[32][33];
    int tx = threadIdx.x, ty = threadIdx.y;
    int bx = blockIdx.x, by = blockIdx.y;
    #pragma unroll
    for (int i = 0; i < 4; ++i) {
        int y = by * 32 + ty + i * 8;
        tile[ty + i * 8][tx] = W[y * ND + bx * 32 + tx];
    }
    __syncthreads();
    #pragma unroll
    for (int i = 0; i < 4; ++i) {
        int e = bx * 32 + ty + i * 8;
        Wt[e * ND + by * 32 + tx] = (_Float16)tile[tx][ty + i * 8];
    }
}

// ---- fused-convert GEMM + tanh + dot(one) -> logits --------------------
// A = many f32, reg-staged with in-flight f32->fp16 convert into swizzled
// LDS (inner loop = R8's proven fp16 path). B = Wt fp16 via gl_lds.
// nb==0 blocks also store their converted A-tile to manyh (written exactly
// once) so out_kernel_h can read fp16. 128x128 tile, BK=64, 32 KB LDS.
__global__ __launch_bounds__(256, 4)
void gemm_logits_f(const float* __restrict__ many, const _Float16* __restrict__ Wt,
                   const float* __restrict__ one, float* __restrict__ logits,
                   _Float16* __restrict__ manyh) {
    __shared__ uint4 LDSQ[2048];          // 32 KB: A-f16 16K | B-f16 16K
    char* Ld = (char*)LDSQ;

    int bid = blockIdx.x;                  // 4096 blocks
    int j = (bid & 7) * 512 + (bid >> 3);  // XCD-chunked, bijective
    int mb = j >> 3, nb = j & 7;           // 8 consecutive j share mb -> L2 reuse
    int m0 = mb * 128, n0 = nb * 128;

    int tid = threadIdx.x;
    int lane = tid & 63, w = tid >> 6;
    int wr = w >> 1, wc = w & 1;           // 2x2 waves, each 64x64
    int l15 = lane & 15, l4 = lane >> 4;

    // A reg-stage mapping: thread handles fp16 chunk (i*256+tid), i=0..3:
    //   row = i*32 + (tid>>3), cc = tid&7  (8 chunks of 16B per 128B fp16 row)
    int arow = tid >> 3, cc = tid & 7;
    int akey = arow & 7;                            // i*32 == 0 mod 8
    const char* aSrc = (const char*)many + ((size_t)(m0 + arow) << 12) + cc * 32;
    char*       mhD  = (char*)manyh + ((size_t)(m0 + arow) << 11) + cc * 16;
    char*       aD   = Ld + arow * 128 + ((cc ^ akey) << 4);   // swizzled dest
    bool wrH = (nb == 0);

    // B via gl_lds (linear dest, src-swizzled)
    const char* bS = (const char*)Wt + ((size_t)(n0 + (tid >> 3)) << 11)
                   + (size_t)(((tid & 7) ^ ((tid >> 3) & 7)) << 4);

    floatx4 acc[4][4] = {};

    #pragma unroll 1
    for (int kb = 0; kb < 1024; kb += 64) {
        // issue B DMA first (fills during A's reg round-trip)
        #pragma unroll
        for (int i = 0; i < 4; ++i)
            GL16(bS + kb * 2 + i * 65536, Ld + 16384 + i * 4096 + tid * 16);
        // A: load f32, convert, ds_write (swizzled), optional manyh store
        #pragma unroll
        for (int i = 0; i < 4; ++i) {
            float4 x = *(const float4*)(aSrc + (size_t)i * 131072 + kb * 4);
            float4 y = *(const float4*)(aSrc + (size_t)i * 131072 + kb * 4 + 16);
            union { fp16x2 p[4]; uint4 u; } o;
            o.p[0] = __builtin_amdgcn_cvt_pkrtz(x.x, x.y);
            o.p[1] = __builtin_amdgcn_cvt_pkrtz(x.z, x.w);
            o.p[2] = __builtin_amdgcn_cvt_pkrtz(y.x, y.y);
            o.p[3] = __builtin_amdgcn_cvt_pkrtz(y.z, y.w);
            *(uint4*)(aD + i * 4096) = o.u;
            if (wrH) *(uint4*)(mhD + (size_t)i * 65536 + kb * 2) = o.u;
        }
        __syncthreads();                   // waits vmcnt (B DMA) + lgkm (ds_write)

        #pragma unroll
        for (int ks = 0; ks < 64; ks += 32) {
            half8v af[4], bf[4];
            #pragma unroll
            for (int mi = 0; mi < 4; ++mi) {
                int r = wr * 64 + mi * 16 + l15;
                int c = (ks >> 3) + l4;
                af[mi] = *(const half8v*)(Ld + r * 128 + ((c ^ (r & 7)) << 4));
            }
            #pragma unroll
            for (int ni = 0; ni < 4; ++ni) {
                int r = wc * 64 + ni * 16 + l15;
                int c = (ks >> 3) + l4;
                bf[ni] = *(const half8v*)(Ld + 16384 + r * 128 + ((c ^ (r & 7)) << 4));
            }
            #pragma unroll
            for (int mi = 0; mi < 4; ++mi)
                #pragma unroll
                for (int ni = 0; ni < 4; ++ni)
                    acc[mi][ni] = __builtin_amdgcn_mfma_f32_16x16x32_f16(
                        af[mi], bf[ni], acc[mi][ni], 0, 0, 0);
        }
        __syncthreads();                   // reads done before next overwrite
    }

    // epilogue: tanh * one, reduce over columns, atomicAdd logits
    int bidx = m0 >> 11;
    float onev[4];
    #pragma unroll
    for (int ni = 0; ni < 4; ++ni)
        onev[ni] = one[(bidx << 10) + n0 + wc * 64 + ni * 16 + l15];

    #pragma unroll
    for (int mi = 0; mi < 4; ++mi) {
        float part[4] = {0.f, 0.f, 0.f, 0.f};
        #pragma unroll
        for (int ni = 0; ni < 4; ++ni)
            #pragma unroll
            for (int b = 0; b < 4; ++b)
                part[b] += fast_tanh(acc[mi][ni][b]) * onev[ni];
        #pragma unroll
        for (int off = 1; off < 16; off <<= 1)
            #pragma unroll
            for (int b = 0; b < 4; ++b)
                part[b] += __shfl_xor(part[b], off, 64);
        #pragma unroll
        for (int b = 0; b < 4; ++b)
            if (l15 == mi * 4 + b)
                atomicAdd(&logits[m0 + wr * 64 + mi * 16 + l4 * 4 + b], part[b]);
    }
}

// ---------------- fallback GEMM (A f32 from global, cvt at frag read) ------
__global__ __launch_bounds__(256, 3)
void gemm_logits(const float* __restrict__ many, const _Float16* __restrict__ Wt,
                 const float* __restrict__ one, float* __restrict__ logits) {
    __shared__ uint4 AsQ[2048];
    __shared__ uint4 BsQ[1024];
    char* AsB = (char*)AsQ;
    char* BsB = (char*)BsQ;

    int bid = blockIdx.x;
    int j = (bid & 7) * 512 + (bid >> 3);
    int mb = j >> 3, nb = j & 7;
    int m0 = mb * 128, n0 = nb * 128;

    int tid = threadIdx.x;
    int lane = tid & 63, w = tid >> 6;
    int wr = w >> 1, wc = w & 1;
    int l15 = lane & 15, l4 = lane >> 4;

    const char* aS = (const char*)many + ((size_t)(m0 + (tid >> 4)) << 12)
        + (size_t)(((tid & 15) ^ ((tid >> 4) & 7)) << 4);
    const char* bS = (const char*)Wt + ((size_t)(n0 + (tid >> 3)) << 11)
        + (size_t)(((tid & 7) ^ ((tid >> 3) & 7)) << 4);
    char* aD = AsB + tid * 16;
    char* bD = BsB + tid * 16;

    floatx4 acc[4][4] = {};

    for (int kb = 0; kb < 1024; kb += 64) {
        #pragma unroll
        for (int i = 0; i < 8; ++i)
            GL16(aS + kb * 4 + i * 65536, aD + i * 4096);
        #pragma unroll
        for (int i = 0; i < 4; ++i)
            GL16(bS + kb * 2 + i * 65536, bD + i * 4096);
        __syncthreads();

        #pragma unroll
        for (int ks = 0; ks < 64; ks += 32) {
            half8v af[4], bf[4];
            #pragma unroll
            for (int mi = 0; mi < 4; ++mi) {
                int r = wr * 64 + mi * 16 + l15;
                int s = l15 & 7;
                const char* base = AsB + r * 256;
                int c0 = (ks >> 2) + l4 * 2;
                float4 x = *(const float4*)(base + (size_t)((c0 ^ s) << 4));
                float4 y = *(const float4*)(base + (size_t)(((c0 + 1) ^ s) << 4));
                union { fp16x2 p[4]; half8v h; } u;
                u.p[0] = __builtin_amdgcn_cvt_pkrtz(x.x, x.y);
                u.p[1] = __builtin_amdgcn_cvt_pkrtz(x.z, x.w);
                u.p[2] = __builtin_amdgcn_cvt_pkrtz(y.x, y.y);
                u.p[3] = __builtin_amdgcn_cvt_pkrtz(y.z, y.w);
                af[mi] = u.h;
            }
            #pragma unroll
            for (int ni = 0; ni < 4; ++ni) {
                int r = wc * 64 + ni * 16 + l15;
                int s = l15 & 7;
                int c = (ks >> 3) + l4;
                bf[ni] = *(const half8v*)(BsB + r * 128 + (size_t)((c ^ s) << 4));
            }
            #pragma unroll
            for (int mi = 0; mi < 4; ++mi)
                #pragma unroll
                for (int ni = 0; ni < 4; ++ni)
                    acc[mi][ni] = __builtin_amdgcn_mfma_f32_16x16x32_f16(
                        af[mi], bf[ni], acc[mi][ni], 0, 0, 0);
        }
        __syncthreads();
    }

    int bidx = m0 >> 11;
    float onev[4];
    #pragma unroll
    for (int ni = 0; ni < 4; ++ni)
        onev[ni] = one[(bidx << 10) + n0 + wc * 64 + ni * 16 + l15];

    #pragma unroll
    for (int mi = 0; mi < 4; ++mi) {
        float part[4] = {0.f, 0.f, 0.f, 0.f};
        #pragma unroll
        for (int ni = 0; ni < 4; ++ni)
            #pragma unroll
            for (int b = 0; b < 4; ++b)
                part[b] += fast_tanh(acc[mi][ni][b]) * onev[ni];
        #pragma unroll
        for (int off = 1; off < 16; off <<= 1)
            #pragma unroll
            for (int b = 0; b < 4; ++b)
                part[b] += __shfl_xor(part[b], off, 64);
        #pragma unroll
        for (int b = 0; b < 4; ++b)
            if (l15 == mi * 4 + b)
                atomicAdd(&logits[m0 + wr * 64 + mi * 16 + l4 * 4 + b], part[b]);
    }
}

// ---------------- softmax over T per batch ----------------
__global__ __launch_bounds__(256)
void softmax_kernel(const float* __restrict__ logits, float* __restrict__ att) {
    int b = blockIdx.x, tid = threadIdx.x;
    const float* lr = logits + (b << 11);
    float lv[8];
    float mx = -1e30f;
    #pragma unroll
    for (int i = 0; i < 8; ++i) { lv[i] = lr[tid + (i << 8)]; mx = fmaxf(mx, lv[i]); }
    #pragma unroll
    for (int off = 1; off < 64; off <<= 1) mx = fmaxf(mx, __shfl_xor(mx, off, 64));
    __shared__ float redm[4];
    __shared__ float reds[4];
    int wv = tid >> 6;
    if ((tid & 63) == 0) redm[wv] = mx;
    __syncthreads();
    mx = fmaxf(fmaxf(redm[0], redm[1]), fmaxf(redm[2], redm[3]));
    float s = 0.f;
    #pragma unroll
    for (int i = 0; i < 8; ++i) { lv[i] = expf(lv[i] - mx); s += lv[i]; }
    #pragma unroll
    for (int off = 1; off < 64; off <<= 1) s += __shfl_xor(s, off, 64);
    if ((tid & 63) == 0) reds[wv] = s;
    __syncthreads();
    s = reds[0] + reds[1] + reds[2] + reds[3];
    float inv = 1.0f / (s + 1e-7f);
    #pragma unroll
    for (int i = 0; i < 8; ++i) att[(b << 11) + tid + (i << 8)] = lv[i] * inv;
}

// ------- result[b][d] = sum_t many[b][t][d] * att[b][t] (fp16 input) -------
__global__ __launch_bounds__(256)
void out_kernel_h(const _Float16* __restrict__ manyh, const float* __restrict__ att,
                  float* __restrict__ out) {
    int b = blockIdx.x >> 4, tch = blockIdx.x & 15;
    int tid = threadIdx.x;
    __shared__ float aw[128];
    if (tid < 128) aw[tid] = att[(b << 11) + tch * 128 + tid];
    __syncthreads();
    const _Float16* mp = manyh + (((size_t)b * NT + tch * 128) << 10) + tid * 4;
    float a0 = 0.f, a1 = 0.f, a2 = 0.f, a3 = 0.f;
    for (int t = 0; t < 128; ++t) {
        float wgt = aw[t];
        union { _Float16 h[4]; uint2 u; } v;
        v.u = *reinterpret_cast<const uint2*>(mp + ((size_t)t << 10));
        a0 = fmaf((float)v.h[0], wgt, a0); a1 = fmaf((float)v.h[1], wgt, a1);
        a2 = fmaf((float)v.h[2], wgt, a2); a3 = fmaf((float)v.h[3], wgt, a3);
    }
    float* op = out + (b << 10) + tid * 4;
    atomicAdd(op + 0, a0); atomicAdd(op + 1, a1);
    atomicAdd(op + 2, a2); atomicAdd(op + 3, a3);
}

// ---------------- fallback out (f32 many) ----------------
__global__ __launch_bounds__(256)
void out_kernel(const float* __restrict__ many, const float* __restrict__ att,
                float* __restrict__ out) {
    int b = blockIdx.x >> 4, tch = blockIdx.x & 15;
    int tid = threadIdx.x;
    __shared__ float aw[128];
    if (tid < 128) aw[tid] = att[(b << 11) + tch * 128 + tid];
    __syncthreads();
    const float* mp = many + (((size_t)b * NT + tch * 128) << 10) + tid * 4;
    float ax = 0.f, ay = 0.f, az = 0.f, aww = 0.f;
    for (int t = 0; t < 128; ++t) {
        float wgt = aw[t];
        float4 v = *reinterpret_cast<const float4*>(mp + ((size_t)t << 10));
        ax = fmaf(v.x, wgt, ax); ay = fmaf(v.y, wgt, ay);
        az = fmaf(v.z, wgt, az); aww = fmaf(v.w, wgt, aww);
    }
    float* op = out + (b << 10) + tid * 4;
    atomicAdd(op + 0, ax); atomicAdd(op + 1, ay);
    atomicAdd(op + 2, az); atomicAdd(op + 3, aww);
}

extern "C" void kernel_launch(void* const* d_in, const int* in_sizes, int n_in,
                              void* d_out, int out_size, void* d_ws, size_t ws_size,
                              hipStream_t stream) {
    const float* one  = (const float*)d_in[0];   // [32][1024]
    const float* many = (const float*)d_in[1];   // [32][2048][1024]
    const float* W    = (const float*)d_in[2];   // [1024][1024]
    float* out = (float*)d_out;                  // [0,32768) result | [32768,98304) att

    size_t wtB = (size_t)ND * ND * 2;            // 2 MB
    size_t lgB = (size_t)NM * 4;                 // 256 KB
    size_t mhB = (size_t)NM * ND * 2;            // 128 MB
    _Float16* Wt     = (_Float16*)d_ws;
    float*    logits = (float*)((char*)d_ws + wtB);
    _Float16* manyh  = (_Float16*)((char*)d_ws + wtB + lgB);
    float*    att    = out + NB * ND;
    bool big = ws_size >= wtB + lgB + mhB;       // harness constant -> deterministic

    zero_kernel<<<256, 256, 0, stream>>>(out, logits);
    wt_kernel<<<dim3(32, 32), dim3(32, 8), 0, stream>>>(W, Wt);
    if (big) {
        gemm_logits_f<<<4096, 256, 0, stream>>>(many, Wt, one, logits, manyh);
        softmax_kernel<<<NB, 256, 0, stream>>>(logits, att);
        out_kernel_h<<<NB * 16, 256, 0, stream>>>(manyh, att, out);
    } else {
        gemm_logits<<<4096, 256, 0, stream>>>(many, Wt, one, logits);
        softmax_kernel<<<NB, 256, 0, stream>>>(logits, att);
        out_kernel<<<NB * 16, 256, 0, stream>>>(many, att, out);
    }
}

// Round 11
// 241.021 us; speedup vs baseline: 1.2257x; 1.2257x over previous
//
#include <hip/hip_runtime.h>
#include <hip/hip_bf16.h>

typedef _Float16 half8v __attribute__((ext_vector_type(8)));
typedef __fp16  fp16x2 __attribute__((ext_vector_type(2)));   // cvt_pkrtz return type
typedef float floatx4 __attribute__((ext_vector_type(4)));

#define NB 32
#define NT 2048
#define ND 1024
#define NM (NB * NT)

// global->LDS direct DMA, 16B per lane. Linear LDS dest; swizzle on the
// GLOBAL source address (rule #21).
#define GL16(g, l)                                                             \
    __builtin_amdgcn_global_load_lds(                                          \
        (const __attribute__((address_space(1))) void*)(g),                    \
        (__attribute__((address_space(3))) void*)(l), 16, 0, 0)

__device__ __forceinline__ float fast_tanh(float x) {
    x = fminf(9.0f, fmaxf(-9.0f, x));
    float e = __builtin_amdgcn_exp2f(x * 2.8853900817779268f); // e^(2x)
    return (e - 1.0f) * __builtin_amdgcn_rcpf(e + 1.0f);
}

// ---------------- zero out + logits ----------------
__global__ __launch_bounds__(256)
void zero_kernel(float* __restrict__ out, float* __restrict__ logits) {
    int i = blockIdx.x * 256 + threadIdx.x;      // grid 256 -> 65536 threads
    logits[i] = 0.f;
    if (i < NB * ND) out[i] = 0.f;
}

// ---------------- W [K][N] f32  ->  Wt [N][K] fp16 ----------------
__global__ __launch_bounds__(256)
void wt_kernel(const float* __restrict__ W, _Float16* __restrict__ Wt) {
    __shared__ float tile[32][33];
    int tx = threadIdx.x, ty = threadIdx.y;
    int bx = blockIdx.x, by = blockIdx.y;
    #pragma unroll
    for (int i = 0; i < 4; ++i) {
        int y = by * 32 + ty + i * 8;
        tile[ty + i * 8][tx] = W[y * ND + bx * 32 + tx];
    }
    __syncthreads();
    #pragma unroll
    for (int i = 0; i < 4; ++i) {
        int e = bx * 32 + ty + i * 8;
        Wt[e * ND + by * 32 + tx] = (_Float16)tile[tx][ty + i * 8];
    }
}

// ---- GEMM + tanh + dot(one) -> logits. A = many f32 via gl_lds in TWO ----
// ---- 16 KB half-K stages (BK=32 each); B = Wt fp16 16 KB per K-64.     ----
// ---- 32 KB LDS total -> 4-5 blocks/CU (the R8-proven occupancy lever). ----
__global__ __launch_bounds__(256, 4)
void gemm_logits(const float* __restrict__ many, const _Float16* __restrict__ Wt,
                 const float* __restrict__ one, float* __restrict__ logits) {
    __shared__ uint4 LDSQ[2048];          // 32 KB: A-f32[128][32] 16K | B-f16[128][64] 16K
    char* Ld = (char*)LDSQ;

    int bid = blockIdx.x;                  // 4096 blocks
    int j = (bid & 7) * 512 + (bid >> 3);  // XCD-chunked, bijective (4096%8==0)
    int mb = j >> 3, nb = j & 7;           // 8 consecutive j share mb -> L2 reuse
    int m0 = mb * 128, n0 = nb * 128;

    int tid = threadIdx.x;
    int lane = tid & 63, w = tid >> 6;
    int wr = w >> 1, wc = w & 1;           // 2x2 waves, each 64x64
    int l15 = lane & 15, l4 = lane >> 4;

    // A: 1024 16B-chunks per half-stage; thread handles chunk i*256+tid (i=0..3):
    //    row = i*32 + (tid>>3), cc = tid&7 (8 chunks per 128B f32 row of 32 k);
    //    src chunk = cc ^ (row&7)  (i*32 == 0 mod 8 -> key i-invariant)
    const char* aS = (const char*)many + ((size_t)(m0 + (tid >> 3)) << 12)
        + (size_t)(((tid & 7) ^ ((tid >> 3) & 7)) << 4);
    // B: 1024 chunks per K-64; row = i*32 + (tid>>3), cc = tid&7; same key.
    const char* bS = (const char*)Wt + ((size_t)(n0 + (tid >> 3)) << 11)
        + (size_t)(((tid & 7) ^ ((tid >> 3) & 7)) << 4);

    floatx4 acc[4][4] = {};

    // one half-K compute: A buf holds k=kb+h*32 .. +32 (f32), B chunk win h*4..
#define CHALF(H) do {                                                          \
        half8v af[4], bf[4];                                                   \
        _Pragma("unroll")                                                      \
        for (int mi = 0; mi < 4; ++mi) {                                       \
            int r = wr * 64 + mi * 16 + l15;                                   \
            int s = r & 7;                                                     \
            const char* base = Ld + r * 128;                                   \
            float4 x = *(const float4*)(base + (((l4 * 2) ^ s) << 4));         \
            float4 y = *(const float4*)(base + (((l4 * 2 + 1) ^ s) << 4));     \
            union { fp16x2 p[4]; half8v h; } u;                                \
            u.p[0] = __builtin_amdgcn_cvt_pkrtz(x.x, x.y);                     \
            u.p[1] = __builtin_amdgcn_cvt_pkrtz(x.z, x.w);                     \
            u.p[2] = __builtin_amdgcn_cvt_pkrtz(y.x, y.y);                     \
            u.p[3] = __builtin_amdgcn_cvt_pkrtz(y.z, y.w);                     \
            af[mi] = u.h;                                                      \
        }                                                                      \
        _Pragma("unroll")                                                      \
        for (int ni = 0; ni < 4; ++ni) {                                       \
            int r = wc * 64 + ni * 16 + l15;                                   \
            int c = (H) * 4 + l4;                                              \
            bf[ni] = *(const half8v*)(Ld + 16384 + r * 128 + ((c ^ (r & 7)) << 4)); \
        }                                                                      \
        _Pragma("unroll")                                                      \
        for (int mi = 0; mi < 4; ++mi)                                         \
            _Pragma("unroll")                                                  \
            for (int ni = 0; ni < 4; ++ni)                                     \
                acc[mi][ni] = __builtin_amdgcn_mfma_f32_16x16x32_f16(          \
                    af[mi], bf[ni], acc[mi][ni], 0, 0, 0);                     \
    } while (0)

    #pragma unroll 1
    for (int kb = 0; kb < 1024; kb += 64) {
        // stage B(kb..kb+64) and A half 0 (kb..kb+32)
        #pragma unroll
        for (int i = 0; i < 4; ++i)
            GL16(bS + kb * 2 + i * 65536, Ld + 16384 + i * 4096 + tid * 16);
        #pragma unroll
        for (int i = 0; i < 4; ++i)
            GL16(aS + kb * 4 + i * 131072, Ld + i * 4096 + tid * 16);
        __syncthreads();                   // DMA drained, tile resident
        CHALF(0);
        __syncthreads();                   // A reads done before overwrite
        #pragma unroll
        for (int i = 0; i < 4; ++i)
            GL16(aS + kb * 4 + 128 + i * 131072, Ld + i * 4096 + tid * 16);
        __syncthreads();                   // A half 1 resident
        CHALF(1);
        __syncthreads();                   // reads done before next kb stage
    }
#undef CHALF

    // epilogue: tanh * one, reduce over columns, atomicAdd logits
    int bidx = m0 >> 11;
    float onev[4];
    #pragma unroll
    for (int ni = 0; ni < 4; ++ni)
        onev[ni] = one[(bidx << 10) + n0 + wc * 64 + ni * 16 + l15];

    #pragma unroll
    for (int mi = 0; mi < 4; ++mi) {
        float part[4] = {0.f, 0.f, 0.f, 0.f};
        #pragma unroll
        for (int ni = 0; ni < 4; ++ni)
            #pragma unroll
            for (int b = 0; b < 4; ++b)
                part[b] += fast_tanh(acc[mi][ni][b]) * onev[ni];
        #pragma unroll
        for (int off = 1; off < 16; off <<= 1)
            #pragma unroll
            for (int b = 0; b < 4; ++b)
                part[b] += __shfl_xor(part[b], off, 64);
        #pragma unroll
        for (int b = 0; b < 4; ++b)
            if (l15 == mi * 4 + b)
                atomicAdd(&logits[m0 + wr * 64 + mi * 16 + l4 * 4 + b], part[b]);
    }
}

// ---------------- softmax over T per batch ----------------
__global__ __launch_bounds__(256)
void softmax_kernel(const float* __restrict__ logits, float* __restrict__ att) {
    int b = blockIdx.x, tid = threadIdx.x;
    const float* lr = logits + (b << 11);
    float lv[8];
    float mx = -1e30f;
    #pragma unroll
    for (int i = 0; i < 8; ++i) { lv[i] = lr[tid + (i << 8)]; mx = fmaxf(mx, lv[i]); }
    #pragma unroll
    for (int off = 1; off < 64; off <<= 1) mx = fmaxf(mx, __shfl_xor(mx, off, 64));
    __shared__ float redm[4];
    __shared__ float reds[4];
    int wv = tid >> 6;
    if ((tid & 63) == 0) redm[wv] = mx;
    __syncthreads();
    mx = fmaxf(fmaxf(redm[0], redm[1]), fmaxf(redm[2], redm[3]));
    float s = 0.f;
    #pragma unroll
    for (int i = 0; i < 8; ++i) { lv[i] = expf(lv[i] - mx); s += lv[i]; }
    #pragma unroll
    for (int off = 1; off < 64; off <<= 1) s += __shfl_xor(s, off, 64);
    if ((tid & 63) == 0) reds[wv] = s;
    __syncthreads();
    s = reds[0] + reds[1] + reds[2] + reds[3];
    float inv = 1.0f / (s + 1e-7f);
    #pragma unroll
    for (int i = 0; i < 8; ++i) att[(b << 11) + tid + (i << 8)] = lv[i] * inv;
}

// ---------------- result[b][d] = sum_t many[b][t][d] * att[b][t] ----------------
__global__ __launch_bounds__(256)
void out_kernel(const float* __restrict__ many, const float* __restrict__ att,
                float* __restrict__ out) {
    int b = blockIdx.x >> 4, tch = blockIdx.x & 15;   // 16 t-chunks of 128
    int tid = threadIdx.x;
    __shared__ float aw[128];
    if (tid < 128) aw[tid] = att[(b << 11) + tch * 128 + tid];
    __syncthreads();
    const float* mp = many + (((size_t)b * NT + tch * 128) << 10) + tid * 4;
    float ax = 0.f, ay = 0.f, az = 0.f, aww = 0.f;
    for (int t = 0; t < 128; ++t) {
        float wgt = aw[t];
        float4 v = *reinterpret_cast<const float4*>(mp + ((size_t)t << 10));
        ax = fmaf(v.x, wgt, ax); ay = fmaf(v.y, wgt, ay);
        az = fmaf(v.z, wgt, az); aww = fmaf(v.w, wgt, aww);
    }
    float* op = out + (b << 10) + tid * 4;
    atomicAdd(op + 0, ax); atomicAdd(op + 1, ay);
    atomicAdd(op + 2, az); atomicAdd(op + 3, aww);
}

extern "C" void kernel_launch(void* const* d_in, const int* in_sizes, int n_in,
                              void* d_out, int out_size, void* d_ws, size_t ws_size,
                              hipStream_t stream) {
    const float* one  = (const float*)d_in[0];   // [32][1024]
    const float* many = (const float*)d_in[1];   // [32][2048][1024]
    const float* W    = (const float*)d_in[2];   // [1024][1024]
    float* out = (float*)d_out;                  // [0,32768) result | [32768,98304) att

    _Float16* Wt     = (_Float16*)d_ws;                              // 2 MB
    float*    logits = (float*)((char*)d_ws + (size_t)ND * ND * 2);  // 256 KB
    float*    att    = out + NB * ND;

    zero_kernel<<<256, 256, 0, stream>>>(out, logits);
    wt_kernel<<<dim3(32, 32), dim3(32, 8), 0, stream>>>(W, Wt);
    gemm_logits<<<4096, 256, 0, stream>>>(many, Wt, one, logits);
    softmax_kernel<<<NB, 256, 0, stream>>>(logits, att);
    out_kernel<<<NB * 16, 256, 0, stream>>>(many, att, out);
}